// Round 7
// baseline (36.025 us; speedup 1.0000x reference)
//
#include <hip/hip_runtime.h>

#define BLOCK 256
#define HW 256
#define OWID 512
#define PCOLS 264    // xp cols -1..262 (full width + filter halo, zero-guarded)
#define PROWS 12     // xp rows ry0..ry0+11 (4 pair-rows + vertical halo)
#define PPITCH 14    // even -> 8B-aligned b64 reads; spreads banks (gcd(14,32)=2)
#define TPITCH 266   // even -> 8B-aligned

typedef float f32x2 __attribute__((ext_vector_type(2)));
typedef float f32x4 __attribute__((ext_vector_type(4)));

__global__ __launch_bounds__(BLOCK) void up2d_kernel(
    const float* __restrict__ x,
    const float* __restrict__ f,
    float* __restrict__ out)
{
    __shared__ float P[PCOLS][PPITCH];  // P[c][r] transposed patch, 14784 B
    __shared__ float T[8][TPITCH];      // vertical-filter result, 8512 B

    const int tid = threadIdx.x;

    // XCD-aware remap (unchanged): XCD k gets contiguous orig-range -> whole
    // images per XCD; consecutive row-bands sequential on one XCD, so halo
    // rows are L2 hits AND the write stream is long-sequential per XCD.
    const int L = blockIdx.x;                       // 0..8191
    const int orig = ((L & 7) << 10) | (L >> 3);    // bijective
    const int bc = orig >> 6;     // 0..127 image
    const int rt = orig & 63;     // 0..63 row-band: output rows 8rt..8rt+7
    const int ry0 = 4 * rt - 1;   // first xp row of patch

    // Effective 17-tap filter: g[d], d = |offset|
    float g[9];
    g[0] = 4.0f * f[7];
#pragma unroll
    for (int k = 1; k <= 7; ++k) g[k] = 2.0f * (f[7 + k] + f[6 + k]);
    g[8] = 2.0f * f[14];

    float wE[9], wO[8];
#pragma unroll
    for (int q = 0; q < 9; ++q) { int d = 8 - 2 * q; wE[q] = g[d < 0 ? -d : d]; }
#pragma unroll
    for (int q = 0; q < 8; ++q) { int d = 7 - 2 * q; wO[q] = g[d < 0 ? -d : d]; }
    const float g7 = g[7], g8 = g[8];

    // ---- Stage 1: load 12 x 264 patch (transposed, zero-guarded) ----
    const float* xc = x + (size_t)bc * (HW * HW);
#pragma unroll
    for (int it = 0; it < 13; ++it) {
        int w = it * BLOCK + tid;
        if (w < PROWS * PCOLS) {
            int r = w / PCOLS;          // 0..11 (consecutive lanes same row -> coalesced)
            int c = w - r * PCOLS;      // 0..263
            int gr = ry0 + r;           // xp row, -1..262
            int gc = c - 1;             // xp col, -1..262
            int sr = gr - 3; sr = sr < 0 ? -sr : sr; sr = sr >= HW ? 2 * HW - 2 - sr : sr;
            int sc = gc - 3; sc = sc < 0 ? -sc : sc; sc = sc >= HW ? 2 * HW - 2 - sc : sc;
            float v = xc[sr * HW + sc];
            if ((unsigned)gr >= 262u || (unsigned)gc >= 262u) v = 0.0f;  // guard slots
            P[c][r] = v;
        }
    }
    __syncthreads();

    // ---- Stage 2: vertical filter; one col per item, 4 pairs (8 rows) ----
    // Window for pair t (abs pair K=4rt+t): rows t..t+8 (E), t+1..t+8 (O).
#pragma unroll
    for (int it = 0; it < 2; ++it) {
        int c = it * BLOCK + tid;
        if (c < PCOLS) {
            f32x2 b0 = *reinterpret_cast<const f32x2*>(&P[c][0]);
            f32x2 b1 = *reinterpret_cast<const f32x2*>(&P[c][2]);
            f32x2 b2 = *reinterpret_cast<const f32x2*>(&P[c][4]);
            f32x2 b3 = *reinterpret_cast<const f32x2*>(&P[c][6]);
            f32x2 b4 = *reinterpret_cast<const f32x2*>(&P[c][8]);
            f32x2 b5 = *reinterpret_cast<const f32x2*>(&P[c][10]);
            float v[12] = {b0.x, b0.y, b1.x, b1.y, b2.x, b2.y,
                           b3.x, b3.y, b4.x, b4.y, b5.x, b5.y};
#pragma unroll
            for (int t = 0; t < 4; ++t) {
                float aE = 0.0f, aO = 0.0f;
#pragma unroll
                for (int q = 0; q < 9; ++q) aE = fmaf(wE[q], v[t + q], aE);
#pragma unroll
                for (int q = 0; q < 8; ++q) aO = fmaf(wO[q], v[t + 1 + q], aO);
                if (rt == 0 && t == 0)  { aE += g7 * v[1]; aO += g8 * v[1]; }   // xp row 0
                if (rt == 63 && t == 3) { aO += g8 * v[10]; }                   // xp row 261
                T[2 * t][c]     = aE;
                T[2 * t + 1][c] = aO;
            }
        }
    }
    __syncthreads();

    // ---- Stage 3: horizontal filter, 4 cols (2 pairs) per item ----
    // 1024 items = 8 rows x 128 col-groups; per-block stores = ONE contiguous
    // 16 KB region (8 full output rows) -> sequential HBM write stream.
    const float inv_s = 0.25231325f;   // 1/sqrt(5*pi)
    float* oc = out + (size_t)bc * ((size_t)OWID * OWID) + (size_t)(8 * rt) * OWID;
#pragma unroll
    for (int it = 0; it < 4; ++it) {
        int w = it * BLOCK + tid;
        int orow = w >> 7;             // 0..7
        int q4 = w & 127;              // 0..127 -> cols 4q4..4q4+3
        float v[10];
#pragma unroll
        for (int q = 0; q < 5; ++q) {
            f32x2 b = *reinterpret_cast<const f32x2*>(&T[orow][2 * q4 + 2 * q]);
            v[2 * q] = b.x; v[2 * q + 1] = b.y;
        }
        float r0 = 0.f, r1 = 0.f, r2 = 0.f, r3 = 0.f;
#pragma unroll
        for (int q = 0; q < 9; ++q) { r0 = fmaf(wE[q], v[q], r0); r2 = fmaf(wE[q], v[q + 1], r2); }
#pragma unroll
        for (int q = 0; q < 8; ++q) { r1 = fmaf(wO[q], v[q + 1], r1); r3 = fmaf(wO[q], v[q + 2], r3); }
        if (q4 == 0)   { r0 += g7 * T[orow][1];   r1 += g8 * T[orow][1]; }   // xp col 0
        if (q4 == 127) { r3 += g8 * T[orow][262]; }                          // xp col 261
        f32x4 o4 = {r0 * inv_s, r1 * inv_s, r2 * inv_s, r3 * inv_s};
        *reinterpret_cast<f32x4*>(&oc[(size_t)orow * OWID + 4 * q4]) = o4;
    }
}

extern "C" void kernel_launch(void* const* d_in, const int* in_sizes, int n_in,
                              void* d_out, int out_size, void* d_ws, size_t ws_size,
                              hipStream_t stream) {
    const float* x = (const float*)d_in[0];
    const float* f = (const float*)d_in[1];
    float* out = (float*)d_out;
    up2d_kernel<<<dim3(8192), BLOCK, 0, stream>>>(x, f, out);
}

// Round 8
// 34.581 us; speedup vs baseline: 1.0418x; 1.0418x over previous
//
#include <hip/hip_runtime.h>

#define BLOCK 256
#define TILE 64
#define PR 40          // TILE/2 + 8 halo (xp-space)
#define HW 256
#define OWID 512

typedef float f32x2 __attribute__((ext_vector_type(2)));

__global__ __launch_bounds__(BLOCK) void up2d_kernel(
    const float* __restrict__ x,
    const float* __restrict__ f,
    float* __restrict__ out)
{
    __shared__ float P[PR][42];       // P[c][r]; pitch 42 (even) -> b64-aligned rows
    __shared__ float T[TILE][42];     // T[orow][c], pitch 42 keeps 8B align

    const int tid = threadIdx.x;

    // XCD-aware remap: 8192 blocks, 8 XCDs (XCD = id % 8). XCD k gets the
    // contiguous orig-range [1024k, 1024(k+1)): 16 whole images, tiles of each
    // image temporally clustered on ONE XCD -> image fetched from HBM once.
    // Load-bearing: removing this costs ~14 us (round-3 A/B).
    const int L = blockIdx.x;                       // 0..8191
    const int orig = ((L & 7) << 10) | (L >> 3);    // bijective
    const int bc   = orig >> 6;    // 0..127  (image = batch*channel)
    const int tile = orig & 63;    // 0..63   (8x8 tiles of 64x64)

    const int ty = (tile >> 3) * TILE;
    const int tx = (tile & 7) * TILE;
    const int ry0 = (ty >> 1) - 1;
    const int rx0 = (tx >> 1) - 1;

    // Effective 17-tap filter: g[d], d = |offset|
    float g[9];
    g[0] = 4.0f * f[7];
#pragma unroll
    for (int k = 1; k <= 7; ++k) g[k] = 2.0f * (f[7 + k] + f[6 + k]);
    g[8] = 2.0f * f[14];

    float wE[9], wO[8];
#pragma unroll
    for (int q = 0; q < 9; ++q) { int d = 8 - 2 * q; wE[q] = g[d < 0 ? -d : d]; }
#pragma unroll
    for (int q = 0; q < 8; ++q) { int d = 7 - 2 * q; wO[q] = g[d < 0 ? -d : d]; }
    const float g7 = g[7], g8 = g[8];

    // ---- Stage 1: load 40x40 patch (transposed, zero-guarded) ----
    const float* xc = x + (size_t)bc * (HW * HW);
#pragma unroll
    for (int it = 0; it < 7; ++it) {
        int w = it * BLOCK + tid;
        if (w < PR * PR) {
            int r = w / PR;
            int c = w - r * PR;
            int gr = ry0 + r, gc = rx0 + c;
            int sr = gr - 3; sr = sr < 0 ? -sr : sr; sr = sr >= HW ? 2 * HW - 2 - sr : sr;
            int sc = gc - 3; sc = sc < 0 ? -sc : sc; sc = sc >= HW ? 2 * HW - 2 - sc : sc;
            float v = xc[sr * HW + sc];
            if ((unsigned)gr >= 262u || (unsigned)gc >= 262u) v = 0.0f;  // guard slots
            P[c][r] = v;
        }
    }
    __syncthreads();

    // ---- Stage 2: vertical filter; 2 pairs (4 out rows) per item ----
    // 640 items = 16 k2 x 40 cols; reads = 5x ds_read_b64 (10-float window)
#pragma unroll
    for (int it = 0; it < 3; ++it) {
        int w = it * BLOCK + tid;
        if (w < 640) {
            int k2 = w / PR;            // 0..15 -> pairs 2k2, 2k2+1
            int c  = w - k2 * PR;       // 0..39
            f32x2 b0 = *reinterpret_cast<const f32x2*>(&P[c][2 * k2]);
            f32x2 b1 = *reinterpret_cast<const f32x2*>(&P[c][2 * k2 + 2]);
            f32x2 b2 = *reinterpret_cast<const f32x2*>(&P[c][2 * k2 + 4]);
            f32x2 b3 = *reinterpret_cast<const f32x2*>(&P[c][2 * k2 + 6]);
            f32x2 b4 = *reinterpret_cast<const f32x2*>(&P[c][2 * k2 + 8]);
            float v[10] = {b0.x, b0.y, b1.x, b1.y, b2.x,
                           b2.y, b3.x, b3.y, b4.x, b4.y};
#pragma unroll
            for (int t = 0; t < 2; ++t) {
                float aE = 0.0f, aO = 0.0f;
#pragma unroll
                for (int q = 0; q < 9; ++q) aE = fmaf(wE[q], v[t + q], aE);
#pragma unroll
                for (int q = 0; q < 8; ++q) aO = fmaf(wO[q], v[t + 1 + q], aO);
                int k = 2 * k2 + t;
                if (ty == 0 && k == 0)    { aE += g7 * v[1]; aO += g8 * v[1]; }
                if (ty == 448 && k == 31) { aO += g8 * v[8]; }   // P[c][38]
                T[2 * k][c]     = aE;
                T[2 * k + 1][c] = aO;
            }
        }
    }
    __syncthreads();

    // ---- Stage 3: horizontal filter, 4 cols (2 pairs) per item ----
    const float inv_s = 0.25231325f;   // 1/sqrt(5*pi)
    float* oc = out + (size_t)bc * ((size_t)OWID * OWID);
#pragma unroll
    for (int it = 0; it < 4; ++it) {
        int w = it * BLOCK + tid;
        int orow = w >> 4;             // 0..63
        int q4 = w & 15;               // 0..15 -> cols 4q4..4q4+3
        float v[10];
#pragma unroll
        for (int q = 0; q < 10; ++q) v[q] = T[orow][2 * q4 + q];  // ds_read_b64 x5
        float r0 = 0.f, r1 = 0.f, r2 = 0.f, r3 = 0.f;
#pragma unroll
        for (int q = 0; q < 9; ++q) { r0 = fmaf(wE[q], v[q], r0); r2 = fmaf(wE[q], v[q + 1], r2); }
#pragma unroll
        for (int q = 0; q < 8; ++q) { r1 = fmaf(wO[q], v[q + 1], r1); r3 = fmaf(wO[q], v[q + 2], r3); }
        if (tx == 0 && q4 == 0)    { r0 += g7 * T[orow][1]; r1 += g8 * T[orow][1]; }
        if (tx == 448 && q4 == 15) { r3 += g8 * T[orow][38]; }
        float4 o4 = make_float4(r0 * inv_s, r1 * inv_s, r2 * inv_s, r3 * inv_s);
        *reinterpret_cast<float4*>(&oc[(size_t)(ty + orow) * OWID + tx + 4 * q4]) = o4;
    }
}

extern "C" void kernel_launch(void* const* d_in, const int* in_sizes, int n_in,
                              void* d_out, int out_size, void* d_ws, size_t ws_size,
                              hipStream_t stream) {
    const float* x = (const float*)d_in[0];
    const float* f = (const float*)d_in[1];
    float* out = (float*)d_out;
    up2d_kernel<<<dim3(8192), BLOCK, 0, stream>>>(x, f, out);
}